// Round 20
// baseline (105.892 us; speedup 1.0000x reference)
//
#include <hip/hip_runtime.h>

#define EPS 1e-6f

typedef unsigned short u16;
typedef u16   u16x4  __attribute__((ext_vector_type(4)));
typedef u16   u16x8  __attribute__((ext_vector_type(8)));
typedef float f32x4  __attribute__((ext_vector_type(4)));
typedef _Float16 f16x8 __attribute__((ext_vector_type(8)));

enum { BR_LIN = 0, BR_R6, BR_R5, BR_MIN, BR_R3, BR_XY, BR_R1, BR_R0 };

// ---------------- helpers ----------------
__device__ __forceinline__ u16 f2h(float f) { return __builtin_bit_cast(u16, (_Float16)f); }

__device__ __forceinline__ f16x8 lds_f16x8(const u16* p) {
  u16x8 r = *(const u16x8*)p;
  return __builtin_bit_cast(f16x8, r);
}

__device__ __forceinline__ f32x4 mfma16(f16x8 a, f16x8 b, f32x4 c) {
  return __builtin_amdgcn_mfma_f32_16x16x32_f16(a, b, c, 0, 0, 0);
}

// hardware transcendentals: v_exp_f32 = 2^x, v_log_f32 = log2(x); 1 instr each.
__device__ __forceinline__ float fexp2(float x) {
  float r; asm("v_exp_f32 %0, %1" : "=v"(r) : "v"(x)); return r;
}
__device__ __forceinline__ float flog2(float x) {
  float r; asm("v_log_f32 %0, %1" : "=v"(r) : "v"(x)); return r;
}

__device__ __forceinline__ float r_poly_f(float a) {
  float d  = 0.5f - a;
  float d2 = d * d;
  float num = 0.25f + 1.65811f * d + 2.15388f * d2 + 8.2844f * d2 * d + 6.16764f * d2 * d2;
  float den = a * (1.0f - a);
  if (fabsf(den) < EPS) den = EPS;
  return num / den;
}

// ---- chain step: leaf-side precompute (carry-independent) + carry-dependent tail ----
// params: p0=[fx,w0,w1,s_lin] p1=[s_mn,s_xy,s_pm,s_pow] p2=[rs,rinv,cp,sx]
__device__ __forceinline__ void leaf_pre(float leaf, f32x4 p0, f32x4 p2,
                                         float& Y, float& w1Y, float& w1ey, float& cply) {
  float fx = p0[0], w1 = p0[2], rs = p2[0], cp = p2[2], sx = p2[3];
  float yy = fminf(fmaxf(leaf, EPS), 1.0f - EPS);
  Y = fmaf(sx, yy, fx);
  float ly = flog2(Y);
  w1Y  = w1 * Y;
  w1ey = w1 * fexp2(rs * ly);
  cply = cp * ly;
}

__device__ __forceinline__ float step_carry(float carry, float Y, float w1Y, float w1ey, float cply,
                                            f32x4 p0, f32x4 p1, f32x4 p2) {
  float fx = p0[0], w0 = p0[1], s_lin = p0[3];
  float s_mn = p1[0], s_xy = p1[1], s_pm = p1[2], s_pow = p1[3];
  float rs = p2[0], rinv = p2[1], cp = p2[2], sx = p2[3];

  float xx = fminf(fmaxf(carry, EPS), 1.0f - EPS);
  float X  = fmaf(sx, xx, fx);
  float lx = flog2(X);
  float pw = fexp2(fmaf(cp, lx, cply));
  float ex = fexp2(rs * lx);
  float s  = fmaf(w0, ex, w1ey);
  float pm = fexp2(rinv * flog2(s));

  float r = s_lin * fmaf(w0, X, w1Y);
  r = fmaf(s_mn, fminf(X, Y), r);
  r = fmaf(s_xy, X * Y, r);
  r = fmaf(s_pm, pm, r);
  r = fmaf(s_pow, pw, r);
  return fmaf(sx, r, fx);
}

// ---------------- kernel 1: Sinkhorn (register-resident) + fused param precompute ----------------
__global__ __launch_bounds__(1024, 4) void sinkhorn_kernel(
    const float* __restrict__ logits, u16* __restrict__ PTf,
    const float* __restrict__ W, const float* __restrict__ Bv,
    float* __restrict__ prm12) {
  const int t  = threadIdx.x;

  // ---- fused param precompute (runs before the register-heavy section) ----
  if (t < 255) {
    int i = t;
    float w0r = W[2 * i], w1r = W[2 * i + 1];
    float m  = fmaxf(w0r, w1r);
    float e0 = expf(w0r - m), e1 = expf(w1r - m);
    float inv = 1.0f / (e0 + e1);
    float w0 = e0 * inv, w1 = e1 * inv;

    float b   = Bv[i];
    float sig = 1.0f / (1.0f + expf(-b));
    float a_fb = sig * 3.0f - 1.0f;

    float a = a_fb;
    if (__builtin_isnan(a)) a = -1.0f;
    a = fminf(fmaxf(a, -1.0f + EPS), 2.0f - EPS);
    int flip = (a < 0.5f - EPS) ? 1 : 0;
    float aa = a;
    if (flip) aa = fminf(fmaxf(1.0f - a, -1.0f + EPS), 2.0f - EPS);

    int br; float c0 = 0.f, c1 = 0.f, c2 = 0.f, c3 = 0.f;
    if (fabsf(aa - 2.0f) < EPS) br = BR_R0;
    else if (aa > 1.25f && aa < 2.0f) {
      br = BR_R1;
      c0 = sqrtf(fmaxf(3.0f / fmaxf(2.0f - aa, EPS) - 1.0f, EPS));
    } else if (fabsf(aa - 1.25f) < EPS) br = BR_XY;
    else if (aa > 1.0f && aa < 1.25f) { br = BR_R3; c0 = 1.25f - aa; c1 = aa - 1.0f; }
    else if (fabsf(aa - 1.0f) < EPS) br = BR_MIN;
    else if (aa >= 0.75f && aa < 1.0f) {
      br = BR_R5;
      float ac = fminf(fmaxf(aa, 0.75f), 1.0f - EPS);
      float ra = r_poly_f(ac);
      if (fabsf(ra) < EPS) ra = EPS;
      c0 = ra; c1 = 1.0f / ra;
    } else if (aa > 0.5f && aa < 0.75f) {
      br = BR_R6;
      c0 = 3.0f - 4.0f * aa; c1 = 4.0f * aa - 2.0f;
      float R = r_poly_f(0.75f);
      if (fabsf(R) < EPS) R = EPS;
      c2 = R; c3 = 1.0f / R;
    } else br = BR_LIN;

    float s_lin = 0.f, s_mn = 0.f, s_xy = 0.f, s_pm = 0.f, s_pow = 0.f;
    float rs = 1.0f, rinv = 1.0f, cp = 0.0f;
    if (br == BR_R1)       { s_pow = 1.0f; cp = c0; }
    else if (br == BR_XY)  { s_xy = 1.0f; }
    else if (br == BR_R3)  { s_mn = 4.0f * c0; s_xy = 4.0f * c1; }
    else if (br == BR_MIN) { s_mn = 1.0f; }
    else if (br == BR_R5)  { s_pm = 1.0f; rs = c0; rinv = c1; }
    else if (br == BR_R6)  { s_lin = c0; s_pm = c1; rs = c2; rinv = c3; }
    else if (br == BR_LIN) { s_lin = 1.0f; }
    // BR_R0: all weights zero

    float* o12 = prm12 + i * 12;
    o12[0] = (float)flip; o12[1] = w0;  o12[2] = w1;   o12[3] = s_lin;
    o12[4] = s_mn;        o12[5] = s_xy; o12[6] = s_pm; o12[7] = s_pow;
    o12[8] = rs;          o12[9] = rinv; o12[10] = cp;  o12[11] = 1.0f - 2.0f * (float)flip;
  }

  // ---- Sinkhorn (register-resident, round-12 known-good) ----
  __shared__ float alpha[256], beta[256];
  __shared__ float psum[256][33];

  const int R  = t >> 5;
  const int C  = t & 31;
  const int r0 = R << 3;

  float e[8][8];
  #pragma unroll
  for (int dr = 0; dr < 8; ++dr) {
    const float* row = logits + (r0 + dr) * 256 + C;
    #pragma unroll
    for (int m = 0; m < 8; ++m) e[dr][m] = __expf(row[m << 5]);
  }

  if (t < 256) beta[t] = 1.0f;
  __syncthreads();

  for (int it = 0; it < 10; ++it) {
    {
      float bv[8], acc[8];
      #pragma unroll
      for (int m = 0; m < 8; ++m) bv[m] = beta[C + (m << 5)];
      #pragma unroll
      for (int dr = 0; dr < 8; ++dr) {
        float s = 0.f;
        #pragma unroll
        for (int m = 0; m < 8; ++m) s += e[dr][m] * bv[m];
        acc[dr] = s;
      }
      #pragma unroll
      for (int dr = 0; dr < 8; ++dr) psum[r0 + dr][C] = acc[dr];
    }
    __syncthreads();
    if (t < 256) {
      float s = 0.f;
      #pragma unroll
      for (int j = 0; j < 32; ++j) s += psum[t][j];
      alpha[t] = 1.0f / s;
    }
    __syncthreads();
    {
      float av[8], acc[8];
      #pragma unroll
      for (int dr = 0; dr < 8; ++dr) av[dr] = alpha[r0 + dr];
      #pragma unroll
      for (int m = 0; m < 8; ++m) {
        float s = 0.f;
        #pragma unroll
        for (int dr = 0; dr < 8; ++dr) s += e[dr][m] * av[dr];
        acc[m] = s;
      }
      #pragma unroll
      for (int m = 0; m < 8; ++m) psum[C + (m << 5)][R] = acc[m];
    }
    __syncthreads();
    if (t < 256) {
      float s = 0.f;
      #pragma unroll
      for (int j = 0; j < 32; ++j) s += psum[t][j];
      beta[t] = 1.0f / s;
    }
    __syncthreads();
  }

  float av[8], bv[8];
  #pragma unroll
  for (int dr = 0; dr < 8; ++dr) av[dr] = alpha[r0 + dr];
  #pragma unroll
  for (int m = 0; m < 8; ++m) bv[m] = beta[C + (m << 5)];

  #pragma unroll
  for (int m = 0; m < 8; ++m) {
    int l = C + (m << 5);
    u16x8 vh;
    #pragma unroll
    for (int dr = 0; dr < 8; ++dr) vh[dr] = f2h(av[dr] * e[dr][m] * bv[m]);
    *(u16x8*)(PTf + l * 256 + r0) = vh;
  }
}

// ---------------- kernel 2: double-buffered fp16 GEMM + fused chain ----------------
// 256 thr = 4 waves (2M x 2N), b-tile 64, K-step 32, swizzled LDS, 4 blocks/CU.
// Double-buffered staging: tile kc lives in buf kc&1; ONE lgkmcnt-only barrier
// per K-step (8 total vs 16). Per segment: prefetch(kc+1) | C(cur) | W(1-cur) | bar.
// C-reads and W-writes share a scheduling region -> compiler interleaves them.
// Chain params read from GLOBAL prm12 (L2-resident, wave-uniform) - no qlds.
// LDS 40960 B: xs0@0(4K) xs1@4096(4K) pt0@8192(16K) pt1@24576(16K);
// epilogue alias cbuf[64][68]@0 (17408; overlaps xs0/xs1/pt0-head only).
#define CSTR 68

#define PREFETCH(KC1)                                                          \
  {                                                                            \
    int k1 = (KC1) << 5;                                                       \
    _Pragma("unroll")                                                          \
    for (int j = 0; j < 2; ++j)                                                \
      xr[j] = *(const f32x4*)(xbase + k1 + ((xsl + 4 * j) << 2));              \
    _Pragma("unroll")                                                          \
    for (int j = 0; j < 4; ++j) {                                              \
      int c = t + 256 * j, r = c >> 2, s = c & 3, g = s ^ ((r >> 1) & 3);      \
      pr[j] = *(const u16x8*)(PTf + r * 256 + k1 + (g << 3));                  \
    }                                                                          \
  }

#define W_WRITE(XS, PT)                                                        \
  {                                                                            \
    _Pragma("unroll")                                                          \
    for (int j = 0; j < 2; ++j) {                                              \
      int slot = xsl + 4 * j;                                                  \
      u16x4 hv;                                                                \
      _Pragma("unroll")                                                        \
      for (int e = 0; e < 4; ++e) hv[e] = f2h(xr[j][e]);                       \
      int g = slot >> 1, sub = slot & 1;                                       \
      *(u16x4*)((XS) + xrow * 32 + ((g ^ ((xrow >> 1) & 3)) << 3) + (sub << 2)) = hv; \
    }                                                                          \
    _Pragma("unroll")                                                          \
    for (int j = 0; j < 4; ++j)                                                \
      *(u16x8*)((PT) + ((t + 256 * j) << 3)) = pr[j];                          \
  }

#define C_PHASE(XS, PT)                                                        \
  {                                                                            \
    f16x8 bh[2];                                                               \
    _Pragma("unroll")                                                          \
    for (int nf = 0; nf < 2; ++nf) {                                           \
      int brow = (wn << 5) + (nf << 4) + bl;                                   \
      bh[nf] = lds_f16x8((XS) + brow * 32 + ((kh ^ ((brow >> 1) & 3)) << 3));  \
    }                                                                          \
    _Pragma("unroll")                                                          \
    for (int mf = 0; mf < 8; ++mf) {                                           \
      int arow = (wm << 7) + (mf << 4) + bl;                                   \
      f16x8 ah = lds_f16x8((PT) + arow * 32 + ((kh ^ ((arow >> 1) & 3)) << 3));\
      _Pragma("unroll")                                                        \
      for (int nf = 0; nf < 2; ++nf)                                           \
        acc[mf][nf] = mfma16(ah, bh[nf], acc[mf][nf]);                         \
    }                                                                          \
  }

#define KBAR() { asm volatile("s_waitcnt lgkmcnt(0)" ::: "memory"); __builtin_amdgcn_s_barrier(); }

__global__ __launch_bounds__(256, 4) void gemm_chain_kernel(
    const float* __restrict__ x, const u16* __restrict__ PTf,
    const float* __restrict__ prm12, float* __restrict__ out) {
  __shared__ __align__(16) char smem[40960];
  u16* xs0 = (u16*)smem;                     // [64][32] fp16 (swizzled groups)
  u16* xs1 = (u16*)(smem + 4096);
  u16* pt0 = (u16*)(smem + 8192);            // [256][32] fp16 (swizzled groups)
  u16* pt1 = (u16*)(smem + 24576);
  float* cbuf = (float*)smem;                // [64][CSTR] epilogue alias

  const int t    = threadIdx.x;
  const int w    = t >> 6;
  const int lane = t & 63;
  const int bl   = lane & 15;
  const int kh   = lane >> 4;
  const int wm   = w >> 1;                   // 0..1 (l half)
  const int wn   = w & 1;                    // 0..1 (b half)
  const int b0   = blockIdx.x * 64;

  const int xrow = t >> 2;                   // 0..63
  const int xsl  = t & 3;                    // base f32x4 slot

  const float* xbase = x + (size_t)(b0 + xrow) * 256;

  f32x4 acc[8][2];
  #pragma unroll
  for (int m = 0; m < 8; ++m) {
    acc[m][0] = f32x4{0.f, 0.f, 0.f, 0.f};
    acc[m][1] = f32x4{0.f, 0.f, 0.f, 0.f};
  }

  f32x4 xr[2];
  u16x8 pr[4];

  // prologue: tile 0 -> buf0
  PREFETCH(0)
  W_WRITE(xs0, pt0)
  KBAR()

  // segments: prefetch(kc+1) | C(tile kc) | W(tile kc+1 -> other buf) | bar
  PREFETCH(1) C_PHASE(xs0, pt0) W_WRITE(xs1, pt1) KBAR()
  PREFETCH(2) C_PHASE(xs1, pt1) W_WRITE(xs0, pt0) KBAR()
  PREFETCH(3) C_PHASE(xs0, pt0) W_WRITE(xs1, pt1) KBAR()
  PREFETCH(4) C_PHASE(xs1, pt1) W_WRITE(xs0, pt0) KBAR()
  PREFETCH(5) C_PHASE(xs0, pt0) W_WRITE(xs1, pt1) KBAR()
  PREFETCH(6) C_PHASE(xs1, pt1) W_WRITE(xs0, pt0) KBAR()
  PREFETCH(7) C_PHASE(xs0, pt0) W_WRITE(xs1, pt1) KBAR()
  C_PHASE(xs1, pt1)

  // ---- fused chain epilogue (params from global prm12; leading __syncthreads
  //      orders cbuf writes after the final C-phase LDS reads) ----
  float carry = 0.0f;

  #pragma unroll
  for (int c = 0; c < 4; ++c) {
    __syncthreads();
    // waves with wm == c>>1 dump l-chunk [64c, 64c+64) into cbuf[l'][b]
    if (wm == (c >> 1)) {
      #pragma unroll
      for (int d = 0; d < 4; ++d) {
        int mf = ((c & 1) << 2) + d;
        #pragma unroll
        for (int nf = 0; nf < 2; ++nf) {
          int bc = (wn << 5) + (nf << 4) + bl;
          #pragma unroll
          for (int r = 0; r < 4; ++r) {
            int lr = (d << 4) + (kh << 2) + r;
            cbuf[lr * CSTR + bc] = acc[mf][nf][r];
          }
        }
      }
    }
    __syncthreads();
    if (t < 64) {
      int lc0 = 0;
      if (c == 0) {
        float v0 = cbuf[0 * CSTR + t];
        float v1 = cbuf[1 * CSTR + t];
        float v2 = cbuf[2 * CSTR + t];
        float v3 = cbuf[3 * CSTR + t];
        carry = v0;
        float vv[3] = {v1, v2, v3};
        #pragma unroll
        for (int u = 0; u < 3; ++u) {
          const float* qn = prm12 + u * 12;
          f32x4 P0 = *(const f32x4*)(qn), P1 = *(const f32x4*)(qn + 4), P2 = *(const f32x4*)(qn + 8);
          float Y, w1Y, w1ey, cply;
          leaf_pre(vv[u], P0, P2, Y, w1Y, w1ey, cply);
          carry = step_carry(carry, Y, w1Y, w1ey, cply, P0, P1, P2);
        }
        lc0 = 4;
      }
      for (int lc = lc0; lc < 64; lc += 4) {
        float v[4];
        #pragma unroll
        for (int u = 0; u < 4; ++u) v[u] = cbuf[(lc + u) * CSTR + t];
        f32x4 P0[4], P1[4], P2[4];
        #pragma unroll
        for (int u = 0; u < 4; ++u) {
          const float* qn = prm12 + ((c << 6) + lc + u - 1) * 12;
          P0[u] = *(const f32x4*)(qn);
          P1[u] = *(const f32x4*)(qn + 4);
          P2[u] = *(const f32x4*)(qn + 8);
        }
        float Y[4], w1Y[4], w1ey[4], cply[4];
        #pragma unroll
        for (int u = 0; u < 4; ++u)
          leaf_pre(v[u], P0[u], P2[u], Y[u], w1Y[u], w1ey[u], cply[u]);
        #pragma unroll
        for (int u = 0; u < 4; ++u)
          carry = step_carry(carry, Y[u], w1Y[u], w1ey[u], cply[u], P0[u], P1[u], P2[u]);
      }
    }
  }
  if (t < 64) out[b0 + t] = carry;
}

// ---------------- launch ----------------
extern "C" void kernel_launch(void* const* d_in, const int* in_sizes, int n_in,
                              void* d_out, int out_size, void* d_ws, size_t ws_size,
                              hipStream_t stream) {
  const float* x       = (const float*)d_in[0];   // (65536, 256)
  const float* logits  = (const float*)d_in[1];   // (256, 256)
  const float* weights = (const float*)d_in[2];   // (255, 2)
  const float* biases  = (const float*)d_in[3];   // (255,)
  float* out = (float*)d_out;                     // (65536, 1)

  char* ws = (char*)d_ws;
  int Btot = in_sizes[0] / 256;                   // 65536

  u16*   PTf   = (u16*)ws;                        // 131072 B (fp16 P^T)
  float* prm12 = (float*)(ws + 131072);           // 12240 B

  sinkhorn_kernel<<<1, 1024, 0, stream>>>(logits, PTf, weights, biases, prm12);
  gemm_chain_kernel<<<Btot / 64, 256, 0, stream>>>(x, PTf, prm12, out);
}

// Round 21
// 69.707 us; speedup vs baseline: 1.5191x; 1.5191x over previous
//
#include <hip/hip_runtime.h>

#define EPS 1e-6f

typedef unsigned short u16;
typedef u16   u16x4  __attribute__((ext_vector_type(4)));
typedef u16   u16x8  __attribute__((ext_vector_type(8)));
typedef float f32x4  __attribute__((ext_vector_type(4)));
typedef _Float16 f16x8 __attribute__((ext_vector_type(8)));

enum { BR_LIN = 0, BR_R6, BR_R5, BR_MIN, BR_R3, BR_XY, BR_R1, BR_R0 };

// ---------------- helpers ----------------
__device__ __forceinline__ u16 f2h(float f) { return __builtin_bit_cast(u16, (_Float16)f); }

__device__ __forceinline__ f16x8 lds_f16x8(const u16* p) {
  u16x8 r = *(const u16x8*)p;
  return __builtin_bit_cast(f16x8, r);
}

__device__ __forceinline__ f32x4 mfma16(f16x8 a, f16x8 b, f32x4 c) {
  return __builtin_amdgcn_mfma_f32_16x16x32_f16(a, b, c, 0, 0, 0);
}

// hardware transcendentals: v_exp_f32 = 2^x, v_log_f32 = log2(x); 1 instr each.
__device__ __forceinline__ float fexp2(float x) {
  float r; asm("v_exp_f32 %0, %1" : "=v"(r) : "v"(x)); return r;
}
__device__ __forceinline__ float flog2(float x) {
  float r; asm("v_log_f32 %0, %1" : "=v"(r) : "v"(x)); return r;
}

__device__ __forceinline__ float r_poly_f(float a) {
  float d  = 0.5f - a;
  float d2 = d * d;
  float num = 0.25f + 1.65811f * d + 2.15388f * d2 + 8.2844f * d2 * d + 6.16764f * d2 * d2;
  float den = a * (1.0f - a);
  if (fabsf(den) < EPS) den = EPS;
  return num / den;
}

// ---- chain step: leaf-side precompute (carry-independent) + carry-dependent tail ----
// params: p0=[fx,w0,w1,s_lin] p1=[s_mn,s_xy,s_pm,s_pow] p2=[rs,rinv,cp,sx]
__device__ __forceinline__ void leaf_pre(float leaf, f32x4 p0, f32x4 p2,
                                         float& Y, float& w1Y, float& w1ey, float& cply) {
  float fx = p0[0], w1 = p0[2], rs = p2[0], cp = p2[2], sx = p2[3];
  float yy = fminf(fmaxf(leaf, EPS), 1.0f - EPS);
  Y = fmaf(sx, yy, fx);
  float ly = flog2(Y);
  w1Y  = w1 * Y;
  w1ey = w1 * fexp2(rs * ly);
  cply = cp * ly;
}

__device__ __forceinline__ float step_carry(float carry, float Y, float w1Y, float w1ey, float cply,
                                            f32x4 p0, f32x4 p1, f32x4 p2) {
  float fx = p0[0], w0 = p0[1], s_lin = p0[3];
  float s_mn = p1[0], s_xy = p1[1], s_pm = p1[2], s_pow = p1[3];
  float rs = p2[0], rinv = p2[1], cp = p2[2], sx = p2[3];

  float xx = fminf(fmaxf(carry, EPS), 1.0f - EPS);
  float X  = fmaf(sx, xx, fx);
  float lx = flog2(X);
  float pw = fexp2(fmaf(cp, lx, cply));
  float ex = fexp2(rs * lx);
  float s  = fmaf(w0, ex, w1ey);
  float pm = fexp2(rinv * flog2(s));

  float r = s_lin * fmaf(w0, X, w1Y);
  r = fmaf(s_mn, fminf(X, Y), r);
  r = fmaf(s_xy, X * Y, r);
  r = fmaf(s_pm, pm, r);
  r = fmaf(s_pow, pw, r);
  return fmaf(sx, r, fx);
}

// ---------------- kernel 1: Sinkhorn (register-resident) + fused param precompute ----------------
__global__ __launch_bounds__(1024, 4) void sinkhorn_kernel(
    const float* __restrict__ logits, u16* __restrict__ PTf,
    const float* __restrict__ W, const float* __restrict__ Bv,
    float* __restrict__ prm12) {
  const int t  = threadIdx.x;

  // ---- fused param precompute (runs before the register-heavy section) ----
  if (t < 255) {
    int i = t;
    float w0r = W[2 * i], w1r = W[2 * i + 1];
    float m  = fmaxf(w0r, w1r);
    float e0 = expf(w0r - m), e1 = expf(w1r - m);
    float inv = 1.0f / (e0 + e1);
    float w0 = e0 * inv, w1 = e1 * inv;

    float b   = Bv[i];
    float sig = 1.0f / (1.0f + expf(-b));
    float a_fb = sig * 3.0f - 1.0f;

    float a = a_fb;
    if (__builtin_isnan(a)) a = -1.0f;
    a = fminf(fmaxf(a, -1.0f + EPS), 2.0f - EPS);
    int flip = (a < 0.5f - EPS) ? 1 : 0;
    float aa = a;
    if (flip) aa = fminf(fmaxf(1.0f - a, -1.0f + EPS), 2.0f - EPS);

    int br; float c0 = 0.f, c1 = 0.f, c2 = 0.f, c3 = 0.f;
    if (fabsf(aa - 2.0f) < EPS) br = BR_R0;
    else if (aa > 1.25f && aa < 2.0f) {
      br = BR_R1;
      c0 = sqrtf(fmaxf(3.0f / fmaxf(2.0f - aa, EPS) - 1.0f, EPS));
    } else if (fabsf(aa - 1.25f) < EPS) br = BR_XY;
    else if (aa > 1.0f && aa < 1.25f) { br = BR_R3; c0 = 1.25f - aa; c1 = aa - 1.0f; }
    else if (fabsf(aa - 1.0f) < EPS) br = BR_MIN;
    else if (aa >= 0.75f && aa < 1.0f) {
      br = BR_R5;
      float ac = fminf(fmaxf(aa, 0.75f), 1.0f - EPS);
      float ra = r_poly_f(ac);
      if (fabsf(ra) < EPS) ra = EPS;
      c0 = ra; c1 = 1.0f / ra;
    } else if (aa > 0.5f && aa < 0.75f) {
      br = BR_R6;
      c0 = 3.0f - 4.0f * aa; c1 = 4.0f * aa - 2.0f;
      float R = r_poly_f(0.75f);
      if (fabsf(R) < EPS) R = EPS;
      c2 = R; c3 = 1.0f / R;
    } else br = BR_LIN;

    float s_lin = 0.f, s_mn = 0.f, s_xy = 0.f, s_pm = 0.f, s_pow = 0.f;
    float rs = 1.0f, rinv = 1.0f, cp = 0.0f;
    if (br == BR_R1)       { s_pow = 1.0f; cp = c0; }
    else if (br == BR_XY)  { s_xy = 1.0f; }
    else if (br == BR_R3)  { s_mn = 4.0f * c0; s_xy = 4.0f * c1; }
    else if (br == BR_MIN) { s_mn = 1.0f; }
    else if (br == BR_R5)  { s_pm = 1.0f; rs = c0; rinv = c1; }
    else if (br == BR_R6)  { s_lin = c0; s_pm = c1; rs = c2; rinv = c3; }
    else if (br == BR_LIN) { s_lin = 1.0f; }
    // BR_R0: all weights zero

    float* o12 = prm12 + i * 12;
    o12[0] = (float)flip; o12[1] = w0;  o12[2] = w1;   o12[3] = s_lin;
    o12[4] = s_mn;        o12[5] = s_xy; o12[6] = s_pm; o12[7] = s_pow;
    o12[8] = rs;          o12[9] = rinv; o12[10] = cp;  o12[11] = 1.0f - 2.0f * (float)flip;
  }

  // ---- Sinkhorn (register-resident, round-12 known-good) ----
  __shared__ float alpha[256], beta[256];
  __shared__ float psum[256][33];

  const int R  = t >> 5;
  const int C  = t & 31;
  const int r0 = R << 3;

  float e[8][8];
  #pragma unroll
  for (int dr = 0; dr < 8; ++dr) {
    const float* row = logits + (r0 + dr) * 256 + C;
    #pragma unroll
    for (int m = 0; m < 8; ++m) e[dr][m] = __expf(row[m << 5]);
  }

  if (t < 256) beta[t] = 1.0f;
  __syncthreads();

  for (int it = 0; it < 10; ++it) {
    {
      float bv[8], acc[8];
      #pragma unroll
      for (int m = 0; m < 8; ++m) bv[m] = beta[C + (m << 5)];
      #pragma unroll
      for (int dr = 0; dr < 8; ++dr) {
        float s = 0.f;
        #pragma unroll
        for (int m = 0; m < 8; ++m) s += e[dr][m] * bv[m];
        acc[dr] = s;
      }
      #pragma unroll
      for (int dr = 0; dr < 8; ++dr) psum[r0 + dr][C] = acc[dr];
    }
    __syncthreads();
    if (t < 256) {
      float s = 0.f;
      #pragma unroll
      for (int j = 0; j < 32; ++j) s += psum[t][j];
      alpha[t] = 1.0f / s;
    }
    __syncthreads();
    {
      float av[8], acc[8];
      #pragma unroll
      for (int dr = 0; dr < 8; ++dr) av[dr] = alpha[r0 + dr];
      #pragma unroll
      for (int m = 0; m < 8; ++m) {
        float s = 0.f;
        #pragma unroll
        for (int dr = 0; dr < 8; ++dr) s += e[dr][m] * av[dr];
        acc[m] = s;
      }
      #pragma unroll
      for (int m = 0; m < 8; ++m) psum[C + (m << 5)][R] = acc[m];
    }
    __syncthreads();
    if (t < 256) {
      float s = 0.f;
      #pragma unroll
      for (int j = 0; j < 32; ++j) s += psum[t][j];
      beta[t] = 1.0f / s;
    }
    __syncthreads();
  }

  float av[8], bv[8];
  #pragma unroll
  for (int dr = 0; dr < 8; ++dr) av[dr] = alpha[r0 + dr];
  #pragma unroll
  for (int m = 0; m < 8; ++m) bv[m] = beta[C + (m << 5)];

  #pragma unroll
  for (int m = 0; m < 8; ++m) {
    int l = C + (m << 5);
    u16x8 vh;
    #pragma unroll
    for (int dr = 0; dr < 8; ++dr) vh[dr] = f2h(av[dr] * e[dr][m] * bv[m]);
    *(u16x8*)(PTf + l * 256 + r0) = vh;
  }
}

// ---------------- kernel 2: fused fp16 GEMM + branchless HW-trans chain ----------------
// Round-19 validated best: 256 thr = 4 waves (2M x 2N), b-tile 64, K-step 32,
// swizzled LDS, 4 blocks/CU, raw s_barrier with lgkmcnt(0)-only waits in the
// k-loop (prefetch loads stay in flight across the post-C barrier).
// Map: xs[64][32]@0 (4K), pt[256][32]@4096 (16K), qlds@20480 (12240);
// epilogue alias cbuf[64][68]@0 (17408).
#define CSTR 68

__global__ __launch_bounds__(256, 4) void gemm_chain_kernel(
    const float* __restrict__ x, const u16* __restrict__ PTf,
    const float* __restrict__ prm12, float* __restrict__ out) {
  __shared__ __align__(16) char smem[32768];
  u16* xs = (u16*)smem;                      // [64][32] fp16 (swizzled groups)
  u16* pt = (u16*)(smem + 4096);             // [256][32] fp16 (swizzled groups)
  float* qlds = (float*)(smem + 20480);      // 3060 floats (node params)
  float* cbuf = (float*)smem;                // [64][CSTR] epilogue alias

  const int t    = threadIdx.x;
  const int w    = t >> 6;
  const int lane = t & 63;
  const int bl   = lane & 15;
  const int kh   = lane >> 4;
  const int wm   = w >> 1;                   // 0..1 (l half)
  const int wn   = w & 1;                    // 0..1 (b half)
  const int b0   = blockIdx.x * 64;

  const int xrow = t >> 2;                   // 0..63
  const int xsl  = t & 3;                    // base f32x4 slot

  // chain params into LDS (region disjoint from staging)
  for (int j = t; j < 3060; j += 256) qlds[j] = prm12[j];

  f32x4 acc[8][2];
  #pragma unroll
  for (int m = 0; m < 8; ++m) {
    acc[m][0] = f32x4{0.f, 0.f, 0.f, 0.f};
    acc[m][1] = f32x4{0.f, 0.f, 0.f, 0.f};
  }

  f32x4 xr[2];
  u16x8 pr[4];

  // prologue: prefetch tile 0 (PT with pre-swizzled source)
  #pragma unroll
  for (int j = 0; j < 2; ++j)
    xr[j] = *(const f32x4*)(x + (b0 + xrow) * 256 + ((xsl + 4 * j) << 2));
  #pragma unroll
  for (int j = 0; j < 4; ++j) {
    int c = t + 256 * j, r = c >> 2, s = c & 3, g = s ^ ((r >> 1) & 3);
    pr[j] = *(const u16x8*)(PTf + r * 256 + (g << 3));
  }

  for (int kc = 0; kc < 8; ++kc) {
    // ---- W phase: write prefetched tile to LDS ----
    #pragma unroll
    for (int j = 0; j < 2; ++j) {
      int slot = xsl + 4 * j;
      u16x4 hv;
      #pragma unroll
      for (int e = 0; e < 4; ++e) hv[e] = f2h(xr[j][e]);
      int g = slot >> 1, sub = slot & 1;
      *(u16x4*)(xs + xrow * 32 + ((g ^ ((xrow >> 1) & 3)) << 3) + (sub << 2)) = hv;
    }
    #pragma unroll
    for (int j = 0; j < 4; ++j)
      *(u16x8*)(pt + ((t + 256 * j) << 3)) = pr[j];   // linear (content pre-swizzled)

    // post-W barrier: LDS writes must be visible; do NOT drain vmcnt
    asm volatile("s_waitcnt lgkmcnt(0)" ::: "memory");
    __builtin_amdgcn_s_barrier();

    // ---- prefetch next tile (issued here; flies across the post-C barrier) ----
    if (kc < 7) {
      int k1 = (kc + 1) << 5;
      #pragma unroll
      for (int j = 0; j < 2; ++j)
        xr[j] = *(const f32x4*)(x + (b0 + xrow) * 256 + k1 + ((xsl + 4 * j) << 2));
      #pragma unroll
      for (int j = 0; j < 4; ++j) {
        int c = t + 256 * j, r = c >> 2, s = c & 3, g = s ^ ((r >> 1) & 3);
        pr[j] = *(const u16x8*)(PTf + r * 256 + k1 + (g << 3));
      }
    }

    // ---- C phase ----
    f16x8 bh[2];
    #pragma unroll
    for (int nf = 0; nf < 2; ++nf) {
      int brow = (wn << 5) + (nf << 4) + bl;
      bh[nf] = lds_f16x8(xs + brow * 32 + ((kh ^ ((brow >> 1) & 3)) << 3));
    }
    #pragma unroll
    for (int mf = 0; mf < 8; ++mf) {
      int arow = (wm << 7) + (mf << 4) + bl;
      f16x8 ah = lds_f16x8(pt + arow * 32 + ((kh ^ ((arow >> 1) & 3)) << 3));
      #pragma unroll
      for (int nf = 0; nf < 2; ++nf)
        acc[mf][nf] = mfma16(ah, bh[nf], acc[mf][nf]);
    }

    // post-C barrier: all frag reads already consumed by MFMAs; no vmcnt drain
    asm volatile("s_waitcnt lgkmcnt(0)" ::: "memory");
    __builtin_amdgcn_s_barrier();
  }

  // ---- fused chain epilogue (full __syncthreads; nothing in flight) ----
  float carry = 0.0f;

  #pragma unroll
  for (int c = 0; c < 4; ++c) {
    __syncthreads();
    // waves with wm == c>>1 dump l-chunk [64c, 64c+64) into cbuf[l'][b]
    if (wm == (c >> 1)) {
      #pragma unroll
      for (int d = 0; d < 4; ++d) {
        int mf = ((c & 1) << 2) + d;
        #pragma unroll
        for (int nf = 0; nf < 2; ++nf) {
          int bc = (wn << 5) + (nf << 4) + bl;
          #pragma unroll
          for (int r = 0; r < 4; ++r) {
            int lr = (d << 4) + (kh << 2) + r;
            cbuf[lr * CSTR + bc] = acc[mf][nf][r];
          }
        }
      }
    }
    __syncthreads();
    if (t < 64) {
      int lc0 = 0;
      if (c == 0) {
        float v0 = cbuf[0 * CSTR + t];
        float v1 = cbuf[1 * CSTR + t];
        float v2 = cbuf[2 * CSTR + t];
        float v3 = cbuf[3 * CSTR + t];
        carry = v0;
        float vv[3] = {v1, v2, v3};
        #pragma unroll
        for (int u = 0; u < 3; ++u) {
          const float* qn = qlds + u * 12;
          f32x4 P0 = *(const f32x4*)(qn), P1 = *(const f32x4*)(qn + 4), P2 = *(const f32x4*)(qn + 8);
          float Y, w1Y, w1ey, cply;
          leaf_pre(vv[u], P0, P2, Y, w1Y, w1ey, cply);
          carry = step_carry(carry, Y, w1Y, w1ey, cply, P0, P1, P2);
        }
        lc0 = 4;
      }
      for (int lc = lc0; lc < 64; lc += 4) {
        float v[4];
        #pragma unroll
        for (int u = 0; u < 4; ++u) v[u] = cbuf[(lc + u) * CSTR + t];
        f32x4 P0[4], P1[4], P2[4];
        #pragma unroll
        for (int u = 0; u < 4; ++u) {
          const float* qn = qlds + ((c << 6) + lc + u - 1) * 12;
          P0[u] = *(const f32x4*)(qn);
          P1[u] = *(const f32x4*)(qn + 4);
          P2[u] = *(const f32x4*)(qn + 8);
        }
        float Y[4], w1Y[4], w1ey[4], cply[4];
        #pragma unroll
        for (int u = 0; u < 4; ++u)
          leaf_pre(v[u], P0[u], P2[u], Y[u], w1Y[u], w1ey[u], cply[u]);
        #pragma unroll
        for (int u = 0; u < 4; ++u)
          carry = step_carry(carry, Y[u], w1Y[u], w1ey[u], cply[u], P0[u], P1[u], P2[u]);
      }
    }
  }
  if (t < 64) out[b0 + t] = carry;
}

// ---------------- launch ----------------
extern "C" void kernel_launch(void* const* d_in, const int* in_sizes, int n_in,
                              void* d_out, int out_size, void* d_ws, size_t ws_size,
                              hipStream_t stream) {
  const float* x       = (const float*)d_in[0];   // (65536, 256)
  const float* logits  = (const float*)d_in[1];   // (256, 256)
  const float* weights = (const float*)d_in[2];   // (255, 2)
  const float* biases  = (const float*)d_in[3];   // (255,)
  float* out = (float*)d_out;                     // (65536, 1)

  char* ws = (char*)d_ws;
  int Btot = in_sizes[0] / 256;                   // 65536

  u16*   PTf   = (u16*)ws;                        // 131072 B (fp16 P^T)
  float* prm12 = (float*)(ws + 131072);           // 12240 B

  sinkhorn_kernel<<<1, 1024, 0, stream>>>(logits, PTf, weights, biases, prm12);
  gemm_chain_kernel<<<Btot / 64, 256, 0, stream>>>(x, PTf, prm12, out);
}